// Round 6
// baseline (105.990 us; speedup 1.0000x reference)
//
#include <hip/hip_runtime.h>
#include <math.h>

typedef float f32x4 __attribute__((ext_vector_type(4)));

#define NB2   128
#define NT    1024
#define ND    1024
#define BHALF 64
#define NROWS (NB2 * NT)      // 131072
#define MARGIN_F 200.0f
#define EPS_F    1e-6f

#define BCE_BLOCKS  128           // dispatched FIRST so they aren't stragglers
#define MAGS_BLOCKS (NROWS / 4)   // 32768, one wave per row (round-2/5 proven)
#define PAIR_BLOCKS 1024          // 4096 pairs, 4 per block
#define V_BLOCKS    128

// ws layout (float* view):
// [64 .. 192)            bce per-block partials (128)
// [192 .. 320)           V: V_n[0..63], V_a[0..63]
// [1024 .. 5120)         d matrix (64x64)
// [8192 .. 8192+131072)  mags (128 x 1024)

__device__ __forceinline__ float wave_reduce_sum(float s) {
#pragma unroll
    for (int off = 32; off > 0; off >>= 1)
        s += __shfl_xor(s, off, 64);
    return s;
}

// ---- Stage 1: BCE (first 128 blocks) + mags (one wave per row) ----
// Round-6 change: plain (cached) loads instead of nontemporal — isolating
// the nt bit's effect on read throughput. Everything else identical.
__global__ void main_kernel(const float* __restrict__ feats,
                            const float* __restrict__ scores,
                            const float* __restrict__ targets,
                            float* __restrict__ mags,
                            float* __restrict__ bce_part) {
    const int wave = threadIdx.x >> 6;
    const int lane = threadIdx.x & 63;

    if (blockIdx.x < BCE_BLOCKS) {
        const int b   = blockIdx.x;
        const int idx = b * 256 + threadIdx.x;           // float4 index
        f32x4 l4 = reinterpret_cast<const f32x4*>(scores)[idx];
        f32x4 t4 = reinterpret_cast<const f32x4*>(targets)[idx];
        float s = 0.0f;
#pragma unroll
        for (int c = 0; c < 4; ++c) {
            float l = l4[c], t = t4[c];
            s += fmaxf(l, 0.0f) - l * t + log1pf(expf(-fabsf(l)));
        }
        s = wave_reduce_sum(s);
        __shared__ float lds[4];
        if (lane == 0) lds[wave] = s;
        __syncthreads();
        if (threadIdx.x == 0)
            bce_part[b] = lds[0] + lds[1] + lds[2] + lds[3];
        return;
    }

    const int row = (blockIdx.x - BCE_BLOCKS) * 4 + wave;   // 0..131071
    const float* src = feats + (size_t)row * ND;
    float s = 0.0f;
#pragma unroll
    for (int it = 0; it < 4; ++it) {
        f32x4 v = *reinterpret_cast<const f32x4*>(src + lane * 4 + it * 256);
        s += fabsf(v.x) + fabsf(v.y) + fabsf(v.z) + fabsf(v.w);
    }
    s = wave_reduce_sum(s);
    if (lane == 0) mags[row] = s;
}

// ---- Stage 2: pairwise work, all L2-resident ----
// blocks 0..1023:    dmat[i*64+j] = max(MARGIN - ||n_i - a_j + eps||, 0)^2
// blocks 1024..1151: V[b] = sum_{j != i} ||row_j - row_i + eps||^2 within half
__global__ void pairs_kernel(const float* __restrict__ mags,
                             float* __restrict__ dmat,
                             float* __restrict__ V) {
    __shared__ float p[4];
    const int wave = threadIdx.x >> 6;
    const int lane = threadIdx.x & 63;

    if (blockIdx.x < PAIR_BLOCKS) {
        const int pair = blockIdx.x * 4 + wave;      // 0..4095
        const int i = pair >> 6;
        const int j = pair & 63;
        const float* nf = mags + (size_t)i * NT + lane * 4;
        const float* af = mags + (size_t)(BHALF + j) * NT + lane * 4;
        float s = 0.0f;
#pragma unroll
        for (int it = 0; it < 4; ++it) {
            f32x4 a = *reinterpret_cast<const f32x4*>(nf + it * 256);
            f32x4 b = *reinterpret_cast<const f32x4*>(af + it * 256);
#pragma unroll
            for (int c = 0; c < 4; ++c) {
                float dx = a[c] - b[c] + EPS_F;
                s += dx * dx;
            }
        }
        s = wave_reduce_sum(s);
        if (lane == 0) {
            float dist = sqrtf(s);
            float m = MARGIN_F - dist;
            dmat[pair] = (m > 0.0f) ? m * m : 0.0f;
        }
        return;
    }

    // V blocks: candidate star row i within one half
    const int b    = blockIdx.x - PAIR_BLOCKS;   // 0..127
    const int half = b >> 6;                     // 0 = n-half, 1 = a-half
    const int i    = b & 63;
    const float* rowi = mags + (size_t)(half * BHALF + i) * NT + lane * 4;
    f32x4 ri[4];
#pragma unroll
    for (int it = 0; it < 4; ++it)
        ri[it] = *reinterpret_cast<const f32x4*>(rowi + it * 256);

    float s = 0.0f;
    for (int j = wave; j < BHALF; j += 4) {
        if (j == i) continue;                    // reference excludes sq[star]
        const float* rowj = mags + (size_t)(half * BHALF + j) * NT + lane * 4;
#pragma unroll
        for (int it = 0; it < 4; ++it) {
            f32x4 vj = *reinterpret_cast<const f32x4*>(rowj + it * 256);
#pragma unroll
            for (int c = 0; c < 4; ++c) {
                float dx = vj[c] - ri[it][c] + EPS_F;
                s += dx * dx;
            }
        }
    }
    s = wave_reduce_sum(s);
    if (lane == 0) p[wave] = s;
    __syncthreads();
    if (threadIdx.x == 0)
        V[b] = p[0] + p[1] + p[2] + p[3];
}

// ---- Stage 3: argmin + scalar combine ----
__global__ void __launch_bounds__(1024)
mega_kernel(const float* __restrict__ dmat,
            const float* __restrict__ bce_part,
            const float* __restrict__ V,
            float* __restrict__ out) {
    __shared__ float sval[16];
    __shared__ int   sidx[16];
    __shared__ float bp[2];

    const int t    = threadIdx.x;
    const int wave = t >> 6;
    const int lane = t & 63;

    // argmin over dmat[4096], first-occurrence tie-break
    float best = INFINITY;
    int   bidx = 0x7FFFFFFF;
#pragma unroll
    for (int k = t; k < 4096; k += 1024) {
        float v = dmat[k];
        if (v < best || (v == best && k < bidx)) { best = v; bidx = k; }
    }
#pragma unroll
    for (int off = 32; off > 0; off >>= 1) {
        float v2 = __shfl_xor(best, off, 64);
        int   i2 = __shfl_xor(bidx, off, 64);
        if (v2 < best || (v2 == best && i2 < bidx)) { best = v2; bidx = i2; }
    }
    if (lane == 0) { sval[wave] = best; sidx[wave] = bidx; }

    // bce partial sum (threads 0..127)
    if (t < 128) {
        float s = wave_reduce_sum(bce_part[t]);
        if (lane == 0) bp[wave] = s;
    }
    __syncthreads();

    if (t == 0) {
        float bv = sval[0]; int bi = sidx[0];
        for (int w = 1; w < 16; ++w)
            if (sval[w] < bv || (sval[w] == bv && sidx[w] < bi)) { bv = sval[w]; bi = sidx[w]; }
        const int istar = bi >> 6;
        const int jstar = bi & 63;
        float bce      = (bp[0] + bp[1]) / (float)NROWS;
        float loss_n   = V[istar] / (float)BHALF;
        float loss_a   = V[BHALF + jstar] / (float)BHALF;
        float contrast = 0.001f * bv + loss_n + loss_a;
        out[0] = bce + 0.001f * contrast;
    }
}

extern "C" void kernel_launch(void* const* d_in, const int* in_sizes, int n_in,
                              void* d_out, int out_size, void* d_ws, size_t ws_size,
                              hipStream_t stream) {
    const float* scores  = (const float*)d_in[0];
    const float* feats   = (const float*)d_in[1];
    const float* targets = (const float*)d_in[2];
    float* out      = (float*)d_out;
    float* ws       = (float*)d_ws;
    float* bce_part = ws + 64;
    float* V        = ws + 192;
    float* dmat     = ws + 1024;
    float* mags     = ws + 8192;

    main_kernel <<<BCE_BLOCKS + MAGS_BLOCKS, 256, 0, stream>>>(
        feats, scores, targets, mags, bce_part);
    pairs_kernel<<<PAIR_BLOCKS + V_BLOCKS, 256, 0, stream>>>(mags, dmat, V);
    mega_kernel <<<1, 1024, 0, stream>>>(dmat, bce_part, V, out);
}

// Round 7
// 96.307 us; speedup vs baseline: 1.1005x; 1.1005x over previous
//
#include <hip/hip_runtime.h>
#include <math.h>

typedef float f32x4 __attribute__((ext_vector_type(4)));

#define NB2   128
#define NT    1024
#define ND    1024
#define BHALF 64
#define NROWS (NB2 * NT)      // 131072
#define MARGIN_F 200.0f
#define EPS_F    1e-6f

#define BCE_BLOCKS  128           // dispatched FIRST so they aren't stragglers
#define MAGS_BLOCKS (NROWS / 4)   // 32768, one wave per row (round-2/5 proven)
#define PAIR_BLOCKS 1024          // 4096 pairs, 4 per block
#define V_BLOCKS    128

// ws layout (float* view):
// [64 .. 192)            bce per-block partials (128)
// [192 .. 320)           V: V_n[0..63], V_a[0..63]
// [1024 .. 5120)         d matrix (64x64)
// [8192 .. 8192+131072)  mags (128 x 1024)

// Round-7: exact revert to the round-5 kernel (96.7 us).
// A/B established: nontemporal loads on the feats stream are +9 us vs cached.

__device__ __forceinline__ float wave_reduce_sum(float s) {
#pragma unroll
    for (int off = 32; off > 0; off >>= 1)
        s += __shfl_xor(s, off, 64);
    return s;
}

// ---- Stage 1: BCE (first 128 blocks) + mags (one wave per row) ----
__global__ void main_kernel(const float* __restrict__ feats,
                            const float* __restrict__ scores,
                            const float* __restrict__ targets,
                            float* __restrict__ mags,
                            float* __restrict__ bce_part) {
    const int wave = threadIdx.x >> 6;
    const int lane = threadIdx.x & 63;

    if (blockIdx.x < BCE_BLOCKS) {
        const int b   = blockIdx.x;
        const int idx = b * 256 + threadIdx.x;           // float4 index
        f32x4 l4 = reinterpret_cast<const f32x4*>(scores)[idx];
        f32x4 t4 = reinterpret_cast<const f32x4*>(targets)[idx];
        float s = 0.0f;
#pragma unroll
        for (int c = 0; c < 4; ++c) {
            float l = l4[c], t = t4[c];
            s += fmaxf(l, 0.0f) - l * t + log1pf(expf(-fabsf(l)));
        }
        s = wave_reduce_sum(s);
        __shared__ float lds[4];
        if (lane == 0) lds[wave] = s;
        __syncthreads();
        if (threadIdx.x == 0)
            bce_part[b] = lds[0] + lds[1] + lds[2] + lds[3];
        return;
    }

    const int row = (blockIdx.x - BCE_BLOCKS) * 4 + wave;   // 0..131071
    const float* src = feats + (size_t)row * ND;
    float s = 0.0f;
#pragma unroll
    for (int it = 0; it < 4; ++it) {
        f32x4 v = __builtin_nontemporal_load(
            reinterpret_cast<const f32x4*>(src + lane * 4 + it * 256));
        s += fabsf(v.x) + fabsf(v.y) + fabsf(v.z) + fabsf(v.w);
    }
    s = wave_reduce_sum(s);
    if (lane == 0) mags[row] = s;
}

// ---- Stage 2: pairwise work, all L2-resident ----
// blocks 0..1023:    dmat[i*64+j] = max(MARGIN - ||n_i - a_j + eps||, 0)^2
// blocks 1024..1151: V[b] = sum_{j != i} ||row_j - row_i + eps||^2 within half
__global__ void pairs_kernel(const float* __restrict__ mags,
                             float* __restrict__ dmat,
                             float* __restrict__ V) {
    __shared__ float p[4];
    const int wave = threadIdx.x >> 6;
    const int lane = threadIdx.x & 63;

    if (blockIdx.x < PAIR_BLOCKS) {
        const int pair = blockIdx.x * 4 + wave;      // 0..4095
        const int i = pair >> 6;
        const int j = pair & 63;
        const float* nf = mags + (size_t)i * NT + lane * 4;
        const float* af = mags + (size_t)(BHALF + j) * NT + lane * 4;
        float s = 0.0f;
#pragma unroll
        for (int it = 0; it < 4; ++it) {
            f32x4 a = *reinterpret_cast<const f32x4*>(nf + it * 256);
            f32x4 b = *reinterpret_cast<const f32x4*>(af + it * 256);
#pragma unroll
            for (int c = 0; c < 4; ++c) {
                float dx = a[c] - b[c] + EPS_F;
                s += dx * dx;
            }
        }
        s = wave_reduce_sum(s);
        if (lane == 0) {
            float dist = sqrtf(s);
            float m = MARGIN_F - dist;
            dmat[pair] = (m > 0.0f) ? m * m : 0.0f;
        }
        return;
    }

    // V blocks: candidate star row i within one half
    const int b    = blockIdx.x - PAIR_BLOCKS;   // 0..127
    const int half = b >> 6;                     // 0 = n-half, 1 = a-half
    const int i    = b & 63;
    const float* rowi = mags + (size_t)(half * BHALF + i) * NT + lane * 4;
    f32x4 ri[4];
#pragma unroll
    for (int it = 0; it < 4; ++it)
        ri[it] = *reinterpret_cast<const f32x4*>(rowi + it * 256);

    float s = 0.0f;
    for (int j = wave; j < BHALF; j += 4) {
        if (j == i) continue;                    // reference excludes sq[star]
        const float* rowj = mags + (size_t)(half * BHALF + j) * NT + lane * 4;
#pragma unroll
        for (int it = 0; it < 4; ++it) {
            f32x4 vj = *reinterpret_cast<const f32x4*>(rowj + it * 256);
#pragma unroll
            for (int c = 0; c < 4; ++c) {
                float dx = vj[c] - ri[it][c] + EPS_F;
                s += dx * dx;
            }
        }
    }
    s = wave_reduce_sum(s);
    if (lane == 0) p[wave] = s;
    __syncthreads();
    if (threadIdx.x == 0)
        V[b] = p[0] + p[1] + p[2] + p[3];
}

// ---- Stage 3: argmin + scalar combine ----
__global__ void __launch_bounds__(1024)
mega_kernel(const float* __restrict__ dmat,
            const float* __restrict__ bce_part,
            const float* __restrict__ V,
            float* __restrict__ out) {
    __shared__ float sval[16];
    __shared__ int   sidx[16];
    __shared__ float bp[2];

    const int t    = threadIdx.x;
    const int wave = t >> 6;
    const int lane = t & 63;

    // argmin over dmat[4096], first-occurrence tie-break
    float best = INFINITY;
    int   bidx = 0x7FFFFFFF;
#pragma unroll
    for (int k = t; k < 4096; k += 1024) {
        float v = dmat[k];
        if (v < best || (v == best && k < bidx)) { best = v; bidx = k; }
    }
#pragma unroll
    for (int off = 32; off > 0; off >>= 1) {
        float v2 = __shfl_xor(best, off, 64);
        int   i2 = __shfl_xor(bidx, off, 64);
        if (v2 < best || (v2 == best && i2 < bidx)) { best = v2; bidx = i2; }
    }
    if (lane == 0) { sval[wave] = best; sidx[wave] = bidx; }

    // bce partial sum (threads 0..127)
    if (t < 128) {
        float s = wave_reduce_sum(bce_part[t]);
        if (lane == 0) bp[wave] = s;
    }
    __syncthreads();

    if (t == 0) {
        float bv = sval[0]; int bi = sidx[0];
        for (int w = 1; w < 16; ++w)
            if (sval[w] < bv || (sval[w] == bv && sidx[w] < bi)) { bv = sval[w]; bi = sidx[w]; }
        const int istar = bi >> 6;
        const int jstar = bi & 63;
        float bce      = (bp[0] + bp[1]) / (float)NROWS;
        float loss_n   = V[istar] / (float)BHALF;
        float loss_a   = V[BHALF + jstar] / (float)BHALF;
        float contrast = 0.001f * bv + loss_n + loss_a;
        out[0] = bce + 0.001f * contrast;
    }
}

extern "C" void kernel_launch(void* const* d_in, const int* in_sizes, int n_in,
                              void* d_out, int out_size, void* d_ws, size_t ws_size,
                              hipStream_t stream) {
    const float* scores  = (const float*)d_in[0];
    const float* feats   = (const float*)d_in[1];
    const float* targets = (const float*)d_in[2];
    float* out      = (float*)d_out;
    float* ws       = (float*)d_ws;
    float* bce_part = ws + 64;
    float* V        = ws + 192;
    float* dmat     = ws + 1024;
    float* mags     = ws + 8192;

    main_kernel <<<BCE_BLOCKS + MAGS_BLOCKS, 256, 0, stream>>>(
        feats, scores, targets, mags, bce_part);
    pairs_kernel<<<PAIR_BLOCKS + V_BLOCKS, 256, 0, stream>>>(mags, dmat, V);
    mega_kernel <<<1, 1024, 0, stream>>>(dmat, bce_part, V, out);
}